// Round 12
// baseline (6785.992 us; speedup 1.0000x reference)
//
// v12 — byte-identical to v11 (all-f32 I/O + mixed bf16/f32 ws; untested:
// broker timeout). Theory unchanged; holding stable.
#include <hip/hip_runtime.h>
#include <math.h>

#define B_ 1024
#define S_ 48
#define T_ 32
#define E_ 256
#define H_ 512
#define V_ 96
#define BK 32

typedef unsigned short u16;
typedef __attribute__((ext_vector_type(8))) unsigned short u16v8;
typedef __attribute__((ext_vector_type(4))) unsigned short u16v4;
typedef __attribute__((ext_vector_type(2))) unsigned short u16v2;

__device__ __forceinline__ float b2f(u16 u) {
  union { unsigned int i; float f; } v; v.i = ((unsigned int)u) << 16; return v.f;
}
__device__ __forceinline__ u16 f2b(float f) {   // round-to-nearest-even
  union { float f; unsigned int i; } v; v.f = f;
  unsigned int r = v.i + 0x7FFFu + ((v.i >> 16) & 1u);
  return (u16)(r >> 16);
}
__device__ __forceinline__ float sigmoid_fast(float x) {
  return 1.f / (1.f + __expf(-x));
}
__device__ __forceinline__ float tanh_fast(float x) {
  float e = __expf(2.f * x);
  return 1.f - 2.f / (e + 1.f);
}

// ---------------------------------------------------------------------------
// Fused 4-gate GEMM segment, f32 A (recurrent state) x f32 W (inputs).
// Block tile: 64 batch rows x 32 units x 4 gates, 256 threads,
// per-thread 4x2x4 accumulators. W row-major, gate g/unit j at row g*H_+j.
// ---------------------------------------------------------------------------
__device__ __forceinline__ void gate_seg(
    float (*As)[68], float (*Ws)[36],
    const float* __restrict__ aRow,   // &A[loader_row][0], f32
    const float* __restrict__ Wbase, int ldw, int j0, int Kseg,
    int tid, int tx, int ty, float (&acc)[4][4][2])
{
  const int arow = tid >> 2;
  const int acol = (tid & 3) * 8;
  const int wg  = tid >> 6;          // gate handled by this wave
  const int wj  = (tid >> 1) & 31;
  const int wk  = (tid & 1) * 16;
  const float* wrow = Wbase + (size_t)(wg * H_ + j0 + wj) * ldw + wk;

  for (int k0 = 0; k0 < Kseg; k0 += BK) {
    const float4 a0 = *(const float4*)(aRow + k0 + acol);
    const float4 a1 = *(const float4*)(aRow + k0 + acol + 4);
    const float4 w0 = *(const float4*)(wrow + k0);
    const float4 w1 = *(const float4*)(wrow + k0 + 4);
    const float4 w2 = *(const float4*)(wrow + k0 + 8);
    const float4 w3 = *(const float4*)(wrow + k0 + 12);

    As[acol + 0][arow] = a0.x; As[acol + 1][arow] = a0.y;
    As[acol + 2][arow] = a0.z; As[acol + 3][arow] = a0.w;
    As[acol + 4][arow] = a1.x; As[acol + 5][arow] = a1.y;
    As[acol + 6][arow] = a1.z; As[acol + 7][arow] = a1.w;

    float* wsc = &Ws[wg * BK + wk][wj];
    wsc[ 0 * 36] = w0.x; wsc[ 1 * 36] = w0.y; wsc[ 2 * 36] = w0.z; wsc[ 3 * 36] = w0.w;
    wsc[ 4 * 36] = w1.x; wsc[ 5 * 36] = w1.y; wsc[ 6 * 36] = w1.z; wsc[ 7 * 36] = w1.w;
    wsc[ 8 * 36] = w2.x; wsc[ 9 * 36] = w2.y; wsc[10 * 36] = w2.z; wsc[11 * 36] = w2.w;
    wsc[12 * 36] = w3.x; wsc[13 * 36] = w3.y; wsc[14 * 36] = w3.z; wsc[15 * 36] = w3.w;

    __syncthreads();
    #pragma unroll
    for (int kk = 0; kk < BK; ++kk) {
      const float4 av = *(const float4*)(&As[kk][ty * 4]);
      #pragma unroll
      for (int g = 0; g < 4; ++g) {
        const float2 w = *(const float2*)(&Ws[g * BK + kk][tx * 2]);
        acc[g][0][0] += av.x * w.x; acc[g][0][1] += av.x * w.y;
        acc[g][1][0] += av.y * w.x; acc[g][1][1] += av.y * w.y;
        acc[g][2][0] += av.z * w.x; acc[g][2][1] += av.z * w.y;
        acc[g][3][0] += av.w * w.x; acc[g][3][1] += av.w * w.y;
      }
    }
    __syncthreads();
  }
}

// ---------------------------------------------------------------------------
// Vocab projection: C[v][n] = emb[v][:K].W[n][:K] + bias[n]; v<M=96, n<4H.
// All f32. 64x64 tiles, M-row clamp/guard. Runs once per vocab table.
// ---------------------------------------------------------------------------
__global__ __launch_bounds__(256) void proj_gemm_kernel(
    const float* __restrict__ A,    // emb [M][K] f32
    const float* __restrict__ W,    // [4H][ldw] f32, first K cols used
    int ldw, const float* __restrict__ bias,
    float* __restrict__ C,          // [M][4H] f32
    int M, int K)
{
  __shared__ float As[BK][68];
  __shared__ float Bs[BK][68];
  const int tid = threadIdx.x;
  const int tx = tid & 15, ty = tid >> 4;
  const int m0 = blockIdx.x * 64;
  const int n0 = blockIdx.y * 64;
  float acc[4][4];
  #pragma unroll
  for (int i = 0; i < 4; ++i)
    #pragma unroll
    for (int j = 0; j < 4; ++j) acc[i][j] = 0.f;

  const int lrow = tid >> 2;
  const int lcol = (tid & 3) * 8;
  const int arow = (m0 + lrow < M) ? (m0 + lrow) : (M - 1);  // clamp
  const float* ap = A + (size_t)arow * K + lcol;
  const float* wp = W + (size_t)(n0 + lrow) * ldw + lcol;

  for (int k0 = 0; k0 < K; k0 += BK) {
    const float4 a0 = *(const float4*)(ap + k0);
    const float4 a1 = *(const float4*)(ap + k0 + 4);
    const float4 b0 = *(const float4*)(wp + k0);
    const float4 b1 = *(const float4*)(wp + k0 + 4);
    As[lcol + 0][lrow] = a0.x; As[lcol + 1][lrow] = a0.y;
    As[lcol + 2][lrow] = a0.z; As[lcol + 3][lrow] = a0.w;
    As[lcol + 4][lrow] = a1.x; As[lcol + 5][lrow] = a1.y;
    As[lcol + 6][lrow] = a1.z; As[lcol + 7][lrow] = a1.w;
    Bs[lcol + 0][lrow] = b0.x; Bs[lcol + 1][lrow] = b0.y;
    Bs[lcol + 2][lrow] = b0.z; Bs[lcol + 3][lrow] = b0.w;
    Bs[lcol + 4][lrow] = b1.x; Bs[lcol + 5][lrow] = b1.y;
    Bs[lcol + 6][lrow] = b1.z; Bs[lcol + 7][lrow] = b1.w;
    __syncthreads();
    #pragma unroll
    for (int kk = 0; kk < BK; ++kk) {
      const float4 av = *(const float4*)(&As[kk][ty * 4]);
      const float4 bv = *(const float4*)(&Bs[kk][tx * 4]);
      acc[0][0] += av.x * bv.x; acc[0][1] += av.x * bv.y; acc[0][2] += av.x * bv.z; acc[0][3] += av.x * bv.w;
      acc[1][0] += av.y * bv.x; acc[1][1] += av.y * bv.y; acc[1][2] += av.y * bv.z; acc[1][3] += av.y * bv.w;
      acc[2][0] += av.z * bv.x; acc[2][1] += av.z * bv.y; acc[2][2] += av.z * bv.z; acc[2][3] += av.z * bv.w;
      acc[3][0] += av.w * bv.x; acc[3][1] += av.w * bv.y; acc[3][2] += av.w * bv.z; acc[3][3] += av.w * bv.w;
    }
    __syncthreads();
  }
  #pragma unroll
  for (int mi = 0; mi < 4; ++mi) {
    const int r = m0 + ty * 4 + mi;
    if (r < M) {
      const int n = n0 + tx * 4;
      float4 o;
      o.x = acc[mi][0] + bias[n];     o.y = acc[mi][1] + bias[n + 1];
      o.z = acc[mi][2] + bias[n + 2]; o.w = acc[mi][3] + bias[n + 3];
      *(float4*)(&C[(size_t)r * (4 * H_) + n]) = o;
    }
  }
}

// ---------------------------------------------------------------------------
// Encoder step: g = enc_proj[src_t] + h @ Whh^T ; LSTM cell epilogue.
// h/c f32 ws; enc_out bf16 ws; Whh f32 input. grid (B/64, H/32).
// ---------------------------------------------------------------------------
__global__ __launch_bounds__(256) void enc_step_kernel(
    const int* __restrict__ source, const float* __restrict__ enc_proj,
    const float* __restrict__ Whh,
    const float* __restrict__ h_in, float* __restrict__ h_out,
    float* __restrict__ c, u16* __restrict__ enc_out, int t)
{
  __shared__ float As[BK][68];
  __shared__ float Ws[4 * BK][36];
  const int tid = threadIdx.x;
  const int tx = tid & 15, ty = tid >> 4;
  const int b0 = blockIdx.x * 64;
  const int j0 = blockIdx.y * 32;
  float acc[4][4][2];
  #pragma unroll
  for (int g = 0; g < 4; ++g)
    #pragma unroll
    for (int i = 0; i < 4; ++i) { acc[g][i][0] = 0.f; acc[g][i][1] = 0.f; }

  const int arow = tid >> 2;
  gate_seg(As, Ws, h_in + (size_t)(b0 + arow) * H_, Whh, H_, j0, H_, tid, tx, ty, acc);

  #pragma unroll
  for (int mi = 0; mi < 4; ++mi) {
    const int r = b0 + ty * 4 + mi;
    const int sidx = source[(size_t)r * S_ + t];
    const float* prj = enc_proj + (size_t)sidx * (4 * H_);
    #pragma unroll
    for (int ji = 0; ji < 2; ++ji) {
      const int j = j0 + tx * 2 + ji;
      const float iv = acc[0][mi][ji] + prj[j];
      const float fv = acc[1][mi][ji] + prj[H_ + j];
      const float gv = acc[2][mi][ji] + prj[2 * H_ + j];
      const float ov = acc[3][mi][ji] + prj[3 * H_ + j];
      const float cn = sigmoid_fast(fv) * c[(size_t)r * H_ + j] + sigmoid_fast(iv) * tanh_fast(gv);
      const float hn = sigmoid_fast(ov) * tanh_fast(cn);
      c[(size_t)r * H_ + j] = cn;
      h_out[(size_t)r * H_ + j] = hn;
      enc_out[(size_t)r * S_ * H_ + (size_t)t * H_ + j] = f2b(hn);
    }
  }
}

// ---------------------------------------------------------------------------
// Decoder step: g = dec_proj[tgt_t] + ctx@Wih[:,E:]^T + h@Whh^T ; LSTM cell.
// ctx/h/c f32 ws; dec_hs bf16 ws; Wih/Whh f32 inputs.
// ---------------------------------------------------------------------------
__global__ __launch_bounds__(256) void dec_step_kernel(
    const int* __restrict__ target, const float* __restrict__ dec_proj,
    const float* __restrict__ Wih, const float* __restrict__ Whh,
    const float* __restrict__ ctx,
    const float* __restrict__ h_in, float* __restrict__ h_out,
    float* __restrict__ c, u16* __restrict__ dec_hs, int t)
{
  __shared__ float As[BK][68];
  __shared__ float Ws[4 * BK][36];
  const int tid = threadIdx.x;
  const int tx = tid & 15, ty = tid >> 4;
  const int b0 = blockIdx.x * 64;
  const int j0 = blockIdx.y * 32;
  float acc[4][4][2];
  #pragma unroll
  for (int g = 0; g < 4; ++g)
    #pragma unroll
    for (int i = 0; i < 4; ++i) { acc[g][i][0] = 0.f; acc[g][i][1] = 0.f; }

  const int arow = tid >> 2;
  gate_seg(As, Ws, ctx + (size_t)(b0 + arow) * H_, Wih + E_, E_ + H_, j0, H_, tid, tx, ty, acc);
  gate_seg(As, Ws, h_in + (size_t)(b0 + arow) * H_, Whh, H_, j0, H_, tid, tx, ty, acc);

  #pragma unroll
  for (int mi = 0; mi < 4; ++mi) {
    const int r = b0 + ty * 4 + mi;
    const int tok = target[(size_t)r * T_ + t];
    const float* prj = dec_proj + (size_t)tok * (4 * H_);
    #pragma unroll
    for (int ji = 0; ji < 2; ++ji) {
      const int j = j0 + tx * 2 + ji;
      const float iv = acc[0][mi][ji] + prj[j];
      const float fv = acc[1][mi][ji] + prj[H_ + j];
      const float gv = acc[2][mi][ji] + prj[2 * H_ + j];
      const float ov = acc[3][mi][ji] + prj[3 * H_ + j];
      const float cn = sigmoid_fast(fv) * c[(size_t)r * H_ + j] + sigmoid_fast(iv) * tanh_fast(gv);
      const float hn = sigmoid_fast(ov) * tanh_fast(cn);
      c[(size_t)r * H_ + j] = cn;
      h_out[(size_t)r * H_ + j] = hn;
      dec_hs[(size_t)t * B_ * H_ + (size_t)r * H_ + j] = f2b(hn);
    }
  }
}

// ---------------------------------------------------------------------------
// enc_part = enc_out @ Wa_e^T. A bf16 ws, W f32 input, C bf16 ws.
// 64x64 tile, 4x4/thread, f32 compute.
// ---------------------------------------------------------------------------
__global__ __launch_bounds__(256) void gemm_nt_kernel(
    const u16* __restrict__ A, int lda,
    const float* __restrict__ W, int ldw,
    u16* __restrict__ C, int ldc, int K)
{
  __shared__ float As[BK][68];
  __shared__ float Bs[BK][68];
  const int tid = threadIdx.x;
  const int tx = tid & 15, ty = tid >> 4;
  const size_t m0 = (size_t)blockIdx.x * 64;
  const size_t n0 = (size_t)blockIdx.y * 64;
  float acc[4][4];
  #pragma unroll
  for (int i = 0; i < 4; ++i)
    #pragma unroll
    for (int j = 0; j < 4; ++j) acc[i][j] = 0.f;

  const int lrow = tid >> 2;
  const int lcol = (tid & 3) * 8;
  const u16* ap = A + (m0 + lrow) * lda + lcol;
  const float* wp = W + (n0 + lrow) * ldw + lcol;

  for (int k0 = 0; k0 < K; k0 += BK) {
    const u16v8 a = *(const u16v8*)(ap + k0);
    const float4 b0 = *(const float4*)(wp + k0);
    const float4 b1 = *(const float4*)(wp + k0 + 4);
    #pragma unroll
    for (int i = 0; i < 8; ++i) As[lcol + i][lrow] = b2f(a[i]);
    Bs[lcol + 0][lrow] = b0.x; Bs[lcol + 1][lrow] = b0.y;
    Bs[lcol + 2][lrow] = b0.z; Bs[lcol + 3][lrow] = b0.w;
    Bs[lcol + 4][lrow] = b1.x; Bs[lcol + 5][lrow] = b1.y;
    Bs[lcol + 6][lrow] = b1.z; Bs[lcol + 7][lrow] = b1.w;
    __syncthreads();
    #pragma unroll
    for (int kk = 0; kk < BK; ++kk) {
      const float4 av = *(const float4*)(&As[kk][ty * 4]);
      const float4 bv = *(const float4*)(&Bs[kk][tx * 4]);
      acc[0][0] += av.x * bv.x; acc[0][1] += av.x * bv.y; acc[0][2] += av.x * bv.z; acc[0][3] += av.x * bv.w;
      acc[1][0] += av.y * bv.x; acc[1][1] += av.y * bv.y; acc[1][2] += av.y * bv.z; acc[1][3] += av.y * bv.w;
      acc[2][0] += av.z * bv.x; acc[2][1] += av.z * bv.y; acc[2][2] += av.z * bv.z; acc[2][3] += av.z * bv.w;
      acc[3][0] += av.w * bv.x; acc[3][1] += av.w * bv.y; acc[3][2] += av.w * bv.z; acc[3][3] += av.w * bv.w;
    }
    __syncthreads();
  }
  #pragma unroll
  for (int mi = 0; mi < 4; ++mi) {
    u16v4 r;
    r[0] = f2b(acc[mi][0]); r[1] = f2b(acc[mi][1]);
    r[2] = f2b(acc[mi][2]); r[3] = f2b(acc[mi][3]);
    *(u16v4*)(&C[(m0 + ty * 4 + mi) * ldc + n0 + tx * 4]) = r;
  }
}

// ---------------------------------------------------------------------------
// hp' = h @ Wa_h^T + attn_b. All f32 (h f32 ws, W/bias f32 inputs, hp f32 ws).
// 64x32 tile -> 256 blocks (1/CU).
// ---------------------------------------------------------------------------
__global__ __launch_bounds__(256) void hp_gemm_kernel(
    const float* __restrict__ A,     // h  [B][H] f32
    const float* __restrict__ W,     // attn_W f32, ldw = 2H (first H cols)
    const float* __restrict__ bias,  // attn_b [H] f32
    float* __restrict__ C)           // hp+b  [B][H] f32
{
  __shared__ float As[BK][68];
  __shared__ float Bs[BK][36];
  const int tid = threadIdx.x;
  const int tx = tid & 15, ty = tid >> 4;
  const size_t m0 = (size_t)blockIdx.x * 64;
  const int n0 = blockIdx.y * 32;
  float acc[4][2];
  #pragma unroll
  for (int i = 0; i < 4; ++i) { acc[i][0] = 0.f; acc[i][1] = 0.f; }

  const int lrow = tid >> 2;
  const int lcol = (tid & 3) * 8;
  const float* ap = A + (m0 + lrow) * H_ + lcol;
  const int wn = tid >> 3;          // 0..31
  const int wk = (tid & 7) * 4;     // 0..28
  const float* wp = W + (size_t)(n0 + wn) * (2 * H_) + wk;

  for (int k0 = 0; k0 < H_; k0 += BK) {
    const float4 a0 = *(const float4*)(ap + k0);
    const float4 a1 = *(const float4*)(ap + k0 + 4);
    const float4 w0 = *(const float4*)(wp + k0);
    As[lcol + 0][lrow] = a0.x; As[lcol + 1][lrow] = a0.y;
    As[lcol + 2][lrow] = a0.z; As[lcol + 3][lrow] = a0.w;
    As[lcol + 4][lrow] = a1.x; As[lcol + 5][lrow] = a1.y;
    As[lcol + 6][lrow] = a1.z; As[lcol + 7][lrow] = a1.w;
    Bs[wk + 0][wn] = w0.x; Bs[wk + 1][wn] = w0.y;
    Bs[wk + 2][wn] = w0.z; Bs[wk + 3][wn] = w0.w;
    __syncthreads();
    #pragma unroll
    for (int kk = 0; kk < BK; ++kk) {
      const float4 av = *(const float4*)(&As[kk][ty * 4]);
      const float2 wv = *(const float2*)(&Bs[kk][tx * 2]);
      acc[0][0] += av.x * wv.x; acc[0][1] += av.x * wv.y;
      acc[1][0] += av.y * wv.x; acc[1][1] += av.y * wv.y;
      acc[2][0] += av.z * wv.x; acc[2][1] += av.z * wv.y;
      acc[3][0] += av.w * wv.x; acc[3][1] += av.w * wv.y;
    }
    __syncthreads();
  }
  #pragma unroll
  for (int mi = 0; mi < 4; ++mi) {
    const size_t r = m0 + ty * 4 + mi;
    const int j = n0 + tx * 2;
    C[r * H_ + j]     = acc[mi][0] + bias[j];
    C[r * H_ + j + 1] = acc[mi][1] + bias[j + 1];
  }
}

// ---------------------------------------------------------------------------
// Attention: energy -> softmax -> aw (f32 to d_out) -> ctx (f32 ws).
// hp f32, attn_v f32, enc_part/enc_out bf16. One block per batch row.
// ---------------------------------------------------------------------------
__global__ __launch_bounds__(256) void attn_kernel(
    const float* __restrict__ hp, const float* __restrict__ attn_v,
    const u16* __restrict__ enc_part, const u16* __restrict__ enc_out,
    float* __restrict__ ctx, float* __restrict__ att_out, int t)
{
  const int b = blockIdx.x;
  const int tid = threadIdx.x;
  const int lane = tid & 63;
  const int wave = tid >> 6;
  __shared__ float es[S_];
  __shared__ float aw[S_];

  float hb[8], vv[8];
  {
    const float* hpb = hp + (size_t)b * H_;
    #pragma unroll
    for (int half = 0; half < 2; ++half) {
      const int idx = half * 256 + lane * 4;
      const float4 h4 = *(const float4*)(hpb + idx);
      const float4 v4 = *(const float4*)(attn_v + idx);
      hb[half * 4 + 0] = h4.x; hb[half * 4 + 1] = h4.y;
      hb[half * 4 + 2] = h4.z; hb[half * 4 + 3] = h4.w;
      vv[half * 4 + 0] = v4.x; vv[half * 4 + 1] = v4.y;
      vv[half * 4 + 2] = v4.z; vv[half * 4 + 3] = v4.w;
    }
  }
  for (int s = wave * 12; s < (wave + 1) * 12; ++s) {
    const u16* ep = enc_part + ((size_t)b * S_ + s) * H_;
    const u16v4 e0 = *(const u16v4*)(ep + lane * 4);
    const u16v4 e1 = *(const u16v4*)(ep + 256 + lane * 4);
    float sum = 0.f;
    #pragma unroll
    for (int i = 0; i < 4; ++i) sum += tanh_fast(b2f(e0[i]) + hb[i]) * vv[i];
    #pragma unroll
    for (int i = 0; i < 4; ++i) sum += tanh_fast(b2f(e1[i]) + hb[4 + i]) * vv[4 + i];
    #pragma unroll
    for (int off = 32; off; off >>= 1) sum += __shfl_xor(sum, off, 64);
    if (lane == 0) es[s] = sum;
  }
  __syncthreads();
  if (wave == 0) {
    const float e = (lane < S_) ? es[lane] : -1e30f;
    float m = e;
    #pragma unroll
    for (int off = 32; off; off >>= 1) m = fmaxf(m, __shfl_xor(m, off, 64));
    const float p = (lane < S_) ? __expf(e - m) : 0.f;
    float sum = p;
    #pragma unroll
    for (int off = 32; off; off >>= 1) sum += __shfl_xor(sum, off, 64);
    const float a = p / sum;
    if (lane < S_) {
      aw[lane] = a;
      att_out[(size_t)b * T_ * S_ + (size_t)(t + 1) * S_ + lane] = a;
    }
  }
  __syncthreads();
  {
    const int hh = tid * 2;
    float c0 = 0.f, c1 = 0.f;
    const u16* eo = enc_out + (size_t)b * S_ * H_ + hh;
    #pragma unroll 4
    for (int s = 0; s < S_; ++s) {
      const u16v2 e2 = *(const u16v2*)(eo + (size_t)s * H_);
      const float a = aw[s];
      c0 += a * b2f(e2[0]); c1 += a * b2f(e2[1]);
    }
    ctx[(size_t)b * H_ + hh]     = c0;
    ctx[(size_t)b * H_ + hh + 1] = c1;
  }
}

// ---------------------------------------------------------------------------
// Output projection: pred[b, t+1, :] = dec_hs[t, b, :] @ out_W^T + out_b.
// A bf16 ws; W/bias f32 inputs; pred f32 out. M=31744, N=96, K=512.
// ---------------------------------------------------------------------------
__global__ __launch_bounds__(256) void out_gemm_kernel(
    const u16* __restrict__ dec_hs, const float* __restrict__ out_W,
    const float* __restrict__ out_b, float* __restrict__ pred)
{
  __shared__ float As[BK][68];
  __shared__ float Ws[BK][100];
  const int tid = threadIdx.x;
  const int tx = tid & 15, ty = tid >> 4;
  const size_t m0 = (size_t)blockIdx.x * 64;
  float acc[4][6];
  #pragma unroll
  for (int i = 0; i < 4; ++i)
    #pragma unroll
    for (int j = 0; j < 6; ++j) acc[i][j] = 0.f;

  const int lrow = tid >> 2;
  const int lcol = (tid & 3) * 8;
  const u16* ap = dec_hs + (m0 + lrow) * H_ + lcol;

  for (int k0 = 0; k0 < H_; k0 += BK) {
    const u16v8 a = *(const u16v8*)(ap + k0);
    #pragma unroll
    for (int i = 0; i < 8; ++i) As[lcol + i][lrow] = b2f(a[i]);
    #pragma unroll
    for (int i = 0; i < 3; ++i) {
      const int fid = i * 256 + tid;      // 768 float4 = 96 rows x 8
      const int n = fid >> 3;
      const int kq = fid & 7;
      const float4 w = *(const float4*)(out_W + (size_t)n * H_ + k0 + kq * 4);
      Ws[kq * 4 + 0][n] = w.x; Ws[kq * 4 + 1][n] = w.y;
      Ws[kq * 4 + 2][n] = w.z; Ws[kq * 4 + 3][n] = w.w;
    }
    __syncthreads();
    #pragma unroll
    for (int kk = 0; kk < BK; ++kk) {
      const float4 av = *(const float4*)(&As[kk][ty * 4]);
      const float2 w0 = *(const float2*)(&Ws[kk][tx * 6]);
      const float2 w1 = *(const float2*)(&Ws[kk][tx * 6 + 2]);
      const float2 w2 = *(const float2*)(&Ws[kk][tx * 6 + 4]);
      acc[0][0] += av.x * w0.x; acc[0][1] += av.x * w0.y; acc[0][2] += av.x * w1.x;
      acc[0][3] += av.x * w1.y; acc[0][4] += av.x * w2.x; acc[0][5] += av.x * w2.y;
      acc[1][0] += av.y * w0.x; acc[1][1] += av.y * w0.y; acc[1][2] += av.y * w1.x;
      acc[1][3] += av.y * w1.y; acc[1][4] += av.y * w2.x; acc[1][5] += av.y * w2.y;
      acc[2][0] += av.z * w0.x; acc[2][1] += av.z * w0.y; acc[2][2] += av.z * w1.x;
      acc[2][3] += av.z * w1.y; acc[2][4] += av.z * w2.x; acc[2][5] += av.z * w2.y;
      acc[3][0] += av.w * w0.x; acc[3][1] += av.w * w0.y; acc[3][2] += av.w * w1.x;
      acc[3][3] += av.w * w1.y; acc[3][4] += av.w * w2.x; acc[3][5] += av.w * w2.y;
    }
    __syncthreads();
  }
  #pragma unroll
  for (int mi = 0; mi < 4; ++mi) {
    const size_t r = m0 + ty * 4 + mi;
    const int tt = (int)(r >> 10);
    const int b  = (int)(r & 1023);
    float* dst = pred + (size_t)b * T_ * V_ + (size_t)(tt + 1) * V_ + tx * 6;
    #pragma unroll
    for (int j = 0; j < 6; ++j) dst[j] = acc[mi][j] + out_b[tx * 6 + j];
  }
}

// ---------------------------------------------------------------------------
extern "C" void kernel_launch(void* const* d_in, const int* in_sizes, int n_in,
                              void* d_out, int out_size, void* d_ws, size_t ws_size,
                              hipStream_t stream)
{
  (void)in_sizes; (void)n_in;
  const int*   source  = (const int*)d_in[0];
  const int*   target  = (const int*)d_in[1];
  const float* enc_emb = (const float*)d_in[2];
  const float* enc_Wih = (const float*)d_in[3];
  const float* enc_Whh = (const float*)d_in[4];
  const float* enc_b   = (const float*)d_in[5];
  const float* dec_emb = (const float*)d_in[6];
  const float* dec_Wih = (const float*)d_in[7];
  const float* dec_Whh = (const float*)d_in[8];
  const float* dec_b   = (const float*)d_in[9];
  const float* attn_W  = (const float*)d_in[10];
  const float* attn_b  = (const float*)d_in[11];
  const float* attn_v  = (const float*)d_in[12];
  const float* out_W   = (const float*)d_in[13];
  const float* out_b   = (const float*)d_in[14];

  // bf16 region (big arrays), then f32 region (recurrent state + tables).
  u16* wsu = (u16*)d_ws;
  size_t offu = 0;
  u16* enc_out  = wsu + offu; offu += (size_t)B_ * S_ * H_;       // 25.17M u16
  u16* enc_part = wsu + offu; offu += (size_t)B_ * S_ * H_;       // 25.17M
  u16* dec_hs   = wsu + offu; offu += (size_t)(T_ - 1) * B_ * H_; // 16.25M
  float* wsf = (float*)(wsu + offu);                               // 16B-aligned
  size_t offf = 0;
  float* hbuf0    = wsf + offf; offf += (size_t)B_ * H_;
  float* hbuf1    = wsf + offf; offf += (size_t)B_ * H_;
  float* cbuf     = wsf + offf; offf += (size_t)B_ * H_;
  float* hp       = wsf + offf; offf += (size_t)B_ * H_;
  float* ctx      = wsf + offf; offf += (size_t)B_ * H_;
  float* enc_proj = wsf + offf; offf += (size_t)V_ * 4 * H_;
  float* dec_proj = wsf + offf; offf += (size_t)V_ * 4 * H_;
  const size_t need = offu * sizeof(u16) + offf * sizeof(float);   // 145.2 MB
  if (ws_size < need) return;

  float* pred = (float*)d_out;
  float* att  = (float*)d_out + (size_t)B_ * T_ * V_;

  hipMemsetAsync(d_out, 0, (size_t)out_size * sizeof(float), stream);
  hipMemsetAsync(hbuf0, 0, (size_t)B_ * H_ * sizeof(float), stream);
  hipMemsetAsync(cbuf,  0, (size_t)B_ * H_ * sizeof(float), stream);

  // Vocab-factored input projections: proj[v] = emb[v] @ Wih[:, :E]^T + b
  proj_gemm_kernel<<<dim3(2, (4 * H_) / 64), 256, 0, stream>>>(
      enc_emb, enc_Wih, E_, enc_b, enc_proj, V_, E_);
  proj_gemm_kernel<<<dim3(2, (4 * H_) / 64), 256, 0, stream>>>(
      dec_emb, dec_Wih, E_ + H_, dec_b, dec_proj, V_, E_);

  float* hin  = hbuf0;
  float* hout = hbuf1;
  const dim3 gateGrid(B_ / 64, H_ / 32);

  for (int t = 0; t < S_; ++t) {
    enc_step_kernel<<<gateGrid, 256, 0, stream>>>(
        source, enc_proj, enc_Whh, hin, hout, cbuf, enc_out, t);
    float* tmp = hin; hin = hout; hout = tmp;
  }

  gemm_nt_kernel<<<dim3((B_ * S_) / 64, H_ / 64), 256, 0, stream>>>(
      enc_out, H_, attn_W + H_, 2 * H_, enc_part, H_, H_);

  for (int t = 0; t < T_ - 1; ++t) {
    hp_gemm_kernel<<<dim3(B_ / 64, H_ / 32), 256, 0, stream>>>(
        hin, attn_W, attn_b, hp);
    attn_kernel<<<B_, 256, 0, stream>>>(
        hp, attn_v, enc_part, enc_out, ctx, att, t);
    dec_step_kernel<<<gateGrid, 256, 0, stream>>>(
        target, dec_proj, dec_Wih, dec_Whh, ctx, hin, hout, cbuf, dec_hs, t);
    float* tmp = hin; hin = hout; hout = tmp;
  }

  out_gemm_kernel<<<dim3((T_ - 1) * B_ / 64), 256, 0, stream>>>(
      dec_hs, out_W, out_b, pred);
}